// Round 10
// baseline (266.593 us; speedup 1.0000x reference)
//
#include <hip/hip_runtime.h>
#include <hip/hip_bf16.h>

constexpr int kN    = 100000;   // nodes
constexpr int kE    = 1600000;  // random edges
constexpr int kTotE = kE + kN;  // + self loops
constexpr int kM    = 20000;    // masked rows
constexpr float kSlope = 0.2f;

// bucketed CSR build: buckets of 128 consecutive dst nodes
constexpr int kNB   = (kN + 127) >> 7;          // 782 buckets
constexpr int kBCap = 3072;                      // per-bucket pair capacity (mean 2304)
constexpr int kEB   = 4096;                      // edge-stream elems per scatter block
constexpr int kSB   = (kTotE + kEB - 1) / kEB;   // 416 scatter blocks
constexpr int kG1B  = (kN / 16 + 3) / 4;         // 1563 gemm1 blocks

typedef short short8  __attribute__((ext_vector_type(8)));
typedef float floatx4 __attribute__((ext_vector_type(4)));
typedef float floatx2 __attribute__((ext_vector_type(2)));

__device__ __forceinline__ float bf2f(unsigned short u) {
  union { unsigned int i; float f; } v; v.i = ((unsigned int)u) << 16; return v.f;
}
// unpack a dword holding 2 bf16 -> float2 (2 VALU ops; feeds v_pk_fma_f32)
__device__ __forceinline__ floatx2 ubf2(unsigned int v) {
  union { unsigned int u; float f; } lo, hi;
  lo.u = v << 16; hi.u = v & 0xffff0000u;
  floatx2 r; r.x = lo.f; r.y = hi.f; return r;
}
// HW packed f32->bf16 (v_cvt_pk_bf16_f32 on gfx950), RNE
__device__ __forceinline__ unsigned int packbf2(float lo, float hi) {
  __hip_bfloat162 h = __float22bfloat162_rn(float2{lo, hi});
  union { __hip_bfloat162 v; unsigned int u; } c; c.v = h; return c.u;
}
__device__ __forceinline__ unsigned short f2bf1(float f) {
  return (unsigned short)(packbf2(f, f) & 0xffffu);
}
__device__ __forceinline__ short8 pack8(float4 u, float4 v) {
  union { short8 s; unsigned int w[4]; } r;
  r.w[0] = packbf2(u.x, u.y); r.w[1] = packbf2(u.z, u.w);
  r.w[2] = packbf2(v.x, v.y); r.w[3] = packbf2(v.z, v.w);
  return r.s;
}

// ---------------- setup: 3 weight swizzles + zero bcursor, one dispatch ----------------
__device__ __forceinline__ void wprep1(int idx, const float* W, unsigned short* Wf,
                                       int Fo) {
  int j    = idx & 7;
  int lane = (idx >> 3) & 63;
  int t    = idx >> 9;
  int NT = Fo >> 4;
  int kt = t / NT, nt = t - kt * NT;
  int k = kt * 32 + ((lane >> 4) & 3) * 8 + j;
  int n = nt * 16 + (lane & 15);
  Wf[idx] = f2bf1(W[k * Fo + n]);
}

__global__ __launch_bounds__(256) void k_setup(const float* __restrict__ W1,
                                               const float* __restrict__ W2,
                                               const float* __restrict__ fc1w,
                                               unsigned short* __restrict__ Wf1,
                                               unsigned short* __restrict__ Wf2,
                                               unsigned short* __restrict__ Wf3,
                                               int* __restrict__ bcursor) {
  int gid = blockIdx.x * 256 + threadIdx.x;
  if (gid < kNB) bcursor[gid] = 0;
  if (gid < 16384)      wprep1(gid,          W1,   Wf1, 128);
  else if (gid < 24576) wprep1(gid - 16384,  W2,   Wf2, 64);
  else if (gid < 32768) wprep1(gid - 24576,  fc1w, Wf3, 128);
}

// ---------------- fat kernel: bscatter (blocks < kSB) U gemm1 (rest) ----------------
__global__ __launch_bounds__(256) void k_sg1(const int* __restrict__ esrc,
                                             const int* __restrict__ edst,
                                             int* __restrict__ bucketCursor,
                                             int* __restrict__ pairs,
                                             const float* __restrict__ x,
                                             const unsigned short* __restrict__ Wf,
                                             const float* __restrict__ asrc,
                                             const float* __restrict__ adst,
                                             unsigned short* __restrict__ h1,
                                             float* __restrict__ as, float* __restrict__ ad) {
  __shared__ int smemi[4096];                 // 16 KB overlay
  int t = threadIdx.x;
  if (blockIdx.x < kSB) {
    // ---- bscatter ----
    int* hist    = smemi;
    int* runBase = smemi + kNB;
    int* binCur  = smemi + 2 * kNB;
    int b = blockIdx.x;
    for (int i = t; i < kNB; i += 256) hist[i] = 0;
    __syncthreads();
    int i0 = b * kEB;
#pragma unroll
    for (int k = 0; k < kEB / 256; ++k) {
      int i = i0 + t + k * 256;
      if (i < kTotE) {
        int d = (i < kE) ? edst[i] : (i - kE);
        atomicAdd(&hist[d >> 7], 1);
      }
    }
    __syncthreads();
    for (int i = t; i < kNB; i += 256) {
      int c = hist[i];
      int base = -1;
      if (c) {
        base = atomicAdd(&bucketCursor[i], c);
        if (base + c > kBCap) base = -1;      // overflow guard (never expected)
      }
      runBase[i] = base;
      binCur[i] = 0;
    }
    __syncthreads();
#pragma unroll
    for (int k = 0; k < kEB / 256; ++k) {
      int i = i0 + t + k * 256;
      if (i < kTotE) {
        int s, d;
        if (i < kE) { s = esrc[i]; d = edst[i]; }
        else        { s = d = i - kE; }
        int bin = d >> 7;
        int lp = atomicAdd(&binCur[bin], 1);
        int rb = runBase[bin];
        if (rb >= 0) pairs[(size_t)bin * kBCap + rb + lp] = ((d & 127) << 17) | s;
      }
    }
    return;
  }
  // ---- gemm1: h1[N,128](bf16) = x(fp32) @ W1, + alpha dots ----
  int wave = t >> 6, lane = t & 63;
  int strip = (blockIdx.x - kSB) * 4 + wave;
  if (strip >= kN / 16) return;
  int r0 = strip * 16;
  int m = lane & 15, quad = lane >> 4;
  const float4* xf = (const float4*)(x + (size_t)(r0 + m) * 128);
  short8 a0 = pack8(xf[quad * 2 + 0],  xf[quad * 2 + 1]);
  short8 a1 = pack8(xf[quad * 2 + 8],  xf[quad * 2 + 9]);
  short8 a2 = pack8(xf[quad * 2 + 16], xf[quad * 2 + 17]);
  short8 a3 = pack8(xf[quad * 2 + 24], xf[quad * 2 + 25]);
  const short8* wf = (const short8*)Wf;
  floatx4 acc[8];
#pragma unroll
  for (int nt = 0; nt < 8; ++nt) acc[nt] = floatx4{0.f, 0.f, 0.f, 0.f};
#pragma unroll
  for (int nt = 0; nt < 8; ++nt) {
    acc[nt] = __builtin_amdgcn_mfma_f32_16x16x32_bf16(a0, wf[(0 * 8 + nt) * 64 + lane], acc[nt], 0, 0, 0);
    acc[nt] = __builtin_amdgcn_mfma_f32_16x16x32_bf16(a1, wf[(1 * 8 + nt) * 64 + lane], acc[nt], 0, 0, 0);
    acc[nt] = __builtin_amdgcn_mfma_f32_16x16x32_bf16(a2, wf[(2 * 8 + nt) * 64 + lane], acc[nt], 0, 0, 0);
    acc[nt] = __builtin_amdgcn_mfma_f32_16x16x32_bf16(a3, wf[(3 * 8 + nt) * 64 + lane], acc[nt], 0, 0, 0);
  }
#pragma unroll
  for (int reg = 0; reg < 4; ++reg) {
    float s = 0.f, d = 0.f;
#pragma unroll
    for (int nt = 0; nt < 8; ++nt) {
      float v = acc[nt][reg];
      s += v * asrc[nt * 16 + m];
      d += v * adst[nt * 16 + m];
    }
#pragma unroll
    for (int off = 1; off < 16; off <<= 1) { s += __shfl_xor(s, off); d += __shfl_xor(d, off); }
    if (m == 0) { as[r0 + quad * 4 + reg] = s; ad[r0 + quad * 4 + reg] = d; }
  }
  unsigned short* tw = (unsigned short*)smemi + wave * 2048;
#pragma unroll
  for (int nt = 0; nt < 8; ++nt)
#pragma unroll
    for (int reg = 0; reg < 4; ++reg)
      tw[(quad * 4 + reg) * 128 + nt * 16 + m] = f2bf1(acc[nt][reg]);
  asm volatile("s_waitcnt lgkmcnt(0)" ::: "memory");   // wave-local LDS RAW
  const short8* tr = (const short8*)tw;
  short8* dstp = (short8*)(h1 + (size_t)r0 * 128);
#pragma unroll
  for (int sweep = 0; sweep < 4; ++sweep)
    dstp[sweep * 64 + lane] = tr[sweep * 64 + lane];
}

// ---------------- bucket CSR finalize (in-place: colidx overwrites pairs) ----------------
__global__ __launch_bounds__(256) void k_bucket_csr(int* __restrict__ pairs,
                                                    const int* __restrict__ bucketCursor,
                                                    int* __restrict__ rstart,
                                                    int* __restrict__ degA) {
  __shared__ int pl[kBCap];                   // 12 KB
  __shared__ int colLDS[kBCap];               // 12 KB
  __shared__ int nhist[128], nstart[128], ncur[128], scanbuf[128];
  int b = blockIdx.x, t = threadIdx.x;
  int cnt  = min(bucketCursor[b], kBCap);
  int base = b * kBCap;                       // bucket-strided layout, no global scan
  if (t < 128) { nhist[t] = 0; ncur[t] = 0; }
  __syncthreads();
  for (int j = t; j < cnt; j += 256) {
    int p = pairs[(size_t)base + j];
    pl[j] = p;
    atomicAdd(&nhist[(p >> 17) & 127], 1);
  }
  __syncthreads();
  if (t < 128) scanbuf[t] = nhist[t];
  __syncthreads();
  for (int off = 1; off < 128; off <<= 1) {   // inclusive Hillis-Steele
    int u = (t < 128 && t >= off) ? scanbuf[t - off] : 0;
    __syncthreads();
    if (t < 128) scanbuf[t] += u;
    __syncthreads();
  }
  if (t < 128) nstart[t] = scanbuf[t] - nhist[t];   // exclusive
  __syncthreads();
  int nodes = min(128, kN - b * 128);
  if (t < nodes) {
    rstart[b * 128 + t] = base + nstart[t];
    degA[b * 128 + t]   = nhist[t];
  }
  for (int j = t; j < cnt; j += 256) {
    int p = pl[j];
    int nl = (p >> 17) & 127;
    int lp = atomicAdd(&ncur[nl], 1);
    colLDS[nstart[nl] + lp] = p & 0x1FFFF;
  }
  __syncthreads();
  for (int j = t; j < cnt; j += 256)
    pairs[(size_t)base + j] = colLDS[j];      // in-place: pairs becomes colidx
}

// ---------------- GEMM layer2: h2[N,64](bf16) = o1(bf16) @ W2, + alpha dots ----------------
__global__ __launch_bounds__(256) void k_gemm2(const unsigned short* __restrict__ o1,
                                               const unsigned short* __restrict__ Wf,
                                               const float* __restrict__ asrc,
                                               const float* __restrict__ adst,
                                               unsigned short* __restrict__ h2,
                                               float* __restrict__ as, float* __restrict__ ad) {
  __shared__ unsigned short tile[4][16 * 64];    // 8 KB
  int wave = threadIdx.x >> 6, lane = threadIdx.x & 63;
  int strip = blockIdx.x * 4 + wave;
  if (strip >= kN / 16) return;
  int r0 = strip * 16;
  int m = lane & 15, quad = lane >> 4;
  const short8* xs = (const short8*)(o1 + (size_t)(r0 + m) * 128);
  short8 a0 = xs[quad], a1 = xs[quad + 4], a2 = xs[quad + 8], a3 = xs[quad + 12];
  const short8* wf = (const short8*)Wf;
  floatx4 acc[4];
#pragma unroll
  for (int nt = 0; nt < 4; ++nt) acc[nt] = floatx4{0.f, 0.f, 0.f, 0.f};
#pragma unroll
  for (int nt = 0; nt < 4; ++nt) {
    acc[nt] = __builtin_amdgcn_mfma_f32_16x16x32_bf16(a0, wf[(0 * 4 + nt) * 64 + lane], acc[nt], 0, 0, 0);
    acc[nt] = __builtin_amdgcn_mfma_f32_16x16x32_bf16(a1, wf[(1 * 4 + nt) * 64 + lane], acc[nt], 0, 0, 0);
    acc[nt] = __builtin_amdgcn_mfma_f32_16x16x32_bf16(a2, wf[(2 * 4 + nt) * 64 + lane], acc[nt], 0, 0, 0);
    acc[nt] = __builtin_amdgcn_mfma_f32_16x16x32_bf16(a3, wf[(3 * 4 + nt) * 64 + lane], acc[nt], 0, 0, 0);
  }
#pragma unroll
  for (int reg = 0; reg < 4; ++reg) {
    float s = 0.f, d = 0.f;
#pragma unroll
    for (int nt = 0; nt < 4; ++nt) {
      float v = acc[nt][reg];
      s += v * asrc[nt * 16 + m];
      d += v * adst[nt * 16 + m];
    }
#pragma unroll
    for (int off = 1; off < 16; off <<= 1) { s += __shfl_xor(s, off); d += __shfl_xor(d, off); }
    if (m == 0) { as[r0 + quad * 4 + reg] = s; ad[r0 + quad * 4 + reg] = d; }
  }
  unsigned short* tw = tile[wave];
#pragma unroll
  for (int nt = 0; nt < 4; ++nt)
#pragma unroll
    for (int reg = 0; reg < 4; ++reg)
      tw[(quad * 4 + reg) * 64 + nt * 16 + m] = f2bf1(acc[nt][reg]);
  asm volatile("s_waitcnt lgkmcnt(0)" ::: "memory");
  const short8* tr = (const short8*)tw;
  short8* dstp = (short8*)(h2 + (size_t)r0 * 64);
#pragma unroll
  for (int sweep = 0; sweep < 2; ++sweep)
    dstp[sweep * 64 + lane] = tr[sweep * 64 + lane];
}

// ---------------- aggregation: one wave per dst node ----------------
// Fast path (deg<=64): exact softmax in registers; shfl-broadcast (byte-offset,w);
// float2 accumulators (v_pk_fma_f32); unroll-2 -> 4 gathers in flight.
template <int F, bool MASKED>
__global__ __launch_bounds__(256) void k_agg(const unsigned short* __restrict__ h,
                                             const int* __restrict__ rstart,
                                             const int* __restrict__ degA,
                                             const int* __restrict__ col,
                                             const float* __restrict__ as,
                                             const float* __restrict__ ad,
                                             const float* __restrict__ bias,
                                             unsigned short* __restrict__ out,
                                             const int* __restrict__ maskIdx) {
  __shared__ int2 swb[4][64];                 // fallback only
  int wave = threadIdx.x >> 6, lane = threadIdx.x & 63;
  int idx = blockIdx.x * 4 + wave;
  if (idx >= (MASKED ? kM : kN)) return;
  int n = MASKED ? maskIdx[idx] : idx;
  int nout = MASKED ? idx : n;
  int beg = rstart[n];
  int deg = degA[n];
  float adn = ad[n];

  if (deg <= 64) {
    // ---- fast path ----
    int j = beg + lane;
    int boff = 0; float e = -1e30f;
    if (lane < deg) {
      int s = col[j];
      boff = s << (F == 128 ? 8 : 7);          // row byte offset
      float t = as[s] + adn;
      e = t > 0.f ? t : kSlope * t;            // leaky_relu
    }
    float mx = e;
#pragma unroll
    for (int off = 32; off; off >>= 1) mx = fmaxf(mx, __shfl_xor(mx, off));
    float w0 = __expf(e - mx);                 // invalid lanes -> 0
    float l = w0;
#pragma unroll
    for (int off = 32; off; off >>= 1) l += __shfl_xor(l, off);
    float w = w0 * (1.f / l);
    floatx2 ax0{0.f, 0.f}, ax1{0.f, 0.f}, ax2{0.f, 0.f}, ax3{0.f, 0.f};
    const char* hb = (const char*)h;
    if (F == 128) {
      int quarter = lane >> 4, ql = lane & 15;
      int cnt8 = (deg + 7) & ~7;
#pragma unroll 2
      for (int k = 0; k < cnt8; k += 8) {
        int i1 = k + quarter, i2 = i1 + 4;
        int   b1 = __shfl(boff, i1), b2 = __shfl(boff, i2);
        float w1 = __shfl(w, i1),    w2 = __shfl(w, i2);
        uint4 v1 = *(const uint4*)(hb + b1 + ql * 16);
        uint4 v2 = *(const uint4*)(hb + b2 + ql * 16);
        floatx2 wv1{w1, w1}, wv2{w2, w2};
        ax0 += wv1 * ubf2(v1.x); ax1 += wv1 * ubf2(v1.y);
        ax2 += wv1 * ubf2(v1.z); ax3 += wv1 * ubf2(v1.w);
        ax0 += wv2 * ubf2(v2.x); ax1 += wv2 * ubf2(v2.y);
        ax2 += wv2 * ubf2(v2.z); ax3 += wv2 * ubf2(v2.w);
      }
      float a[8] = {ax0.x, ax0.y, ax1.x, ax1.y, ax2.x, ax2.y, ax3.x, ax3.y};
#pragma unroll
      for (int i = 0; i < 8; ++i) {
        a[i] += __shfl_xor(a[i], 16);
        a[i] += __shfl_xor(a[i], 32);
      }
      if (quarter == 0) {
        float4 b0 = ((const float4*)bias)[ql * 2];
        float4 b1 = ((const float4*)bias)[ql * 2 + 1];
        uint4 pk;
        pk.x = packbf2(fmaxf(a[0] + b0.x, 0.f), fmaxf(a[1] + b0.y, 0.f));
        pk.y = packbf2(fmaxf(a[2] + b0.z, 0.f), fmaxf(a[3] + b0.w, 0.f));
        pk.z = packbf2(fmaxf(a[4] + b1.x, 0.f), fmaxf(a[5] + b1.y, 0.f));
        pk.w = packbf2(fmaxf(a[6] + b1.z, 0.f), fmaxf(a[7] + b1.w, 0.f));
        ((uint4*)(out + (size_t)nout * 128))[ql] = pk;
      }
    } else {
      int eighth = lane >> 3, el = lane & 7;
      int cnt16 = (deg + 15) & ~15;
#pragma unroll 2
      for (int k = 0; k < cnt16; k += 16) {
        int i1 = k + eighth, i2 = i1 + 8;
        int   b1 = __shfl(boff, i1), b2 = __shfl(boff, i2);
        float w1 = __shfl(w, i1),    w2 = __shfl(w, i2);
        uint4 v1 = *(const uint4*)(hb + b1 + el * 16);
        uint4 v2 = *(const uint4*)(hb + b2 + el * 16);
        floatx2 wv1{w1, w1}, wv2{w2, w2};
        ax0 += wv1 * ubf2(v1.x); ax1 += wv1 * ubf2(v1.y);
        ax2 += wv1 * ubf2(v1.z); ax3 += wv1 * ubf2(v1.w);
        ax0 += wv2 * ubf2(v2.x); ax1 += wv2 * ubf2(v2.y);
        ax2 += wv2 * ubf2(v2.z); ax3 += wv2 * ubf2(v2.w);
      }
      float a[8] = {ax0.x, ax0.y, ax1.x, ax1.y, ax2.x, ax2.y, ax3.x, ax3.y};
#pragma unroll
      for (int i = 0; i < 8; ++i) {
        a[i] += __shfl_xor(a[i], 8);
        a[i] += __shfl_xor(a[i], 16);
        a[i] += __shfl_xor(a[i], 32);
      }
      if (eighth == 0) {
        float4 b0 = ((const float4*)bias)[el * 2];
        float4 b1 = ((const float4*)bias)[el * 2 + 1];
        uint4 pk;
        pk.x = packbf2(fmaxf(a[0] + b0.x, 0.f), fmaxf(a[1] + b0.y, 0.f));
        pk.y = packbf2(fmaxf(a[2] + b0.z, 0.f), fmaxf(a[3] + b0.w, 0.f));
        pk.z = packbf2(fmaxf(a[4] + b1.x, 0.f), fmaxf(a[5] + b1.y, 0.f));
        pk.w = packbf2(fmaxf(a[6] + b1.z, 0.f), fmaxf(a[7] + b1.w, 0.f));
        ((uint4*)(out + (size_t)nout * 64))[el] = pk;
      }
    }
    return;
  }

  // ---- fallback: chunked online softmax (deg > 64, essentially never) ----
  int end = beg + deg;
  float m = -1e30f, l = 0.f;
  for (int j0 = beg; j0 < end; j0 += 64) {
    int j = j0 + lane;
    float e = -1e30f;
    if (j < end) {
      int s = col[j];
      float t = as[s] + adn;
      e = t > 0.f ? t : kSlope * t;
    }
    float cm = e;
#pragma unroll
    for (int off = 32; off; off >>= 1) cm = fmaxf(cm, __shfl_xor(cm, off));
    float w = __expf(e - cm);
    float cl = w;
#pragma unroll
    for (int off = 32; off; off >>= 1) cl += __shfl_xor(cl, off);
    float mn = fmaxf(m, cm);
    l = l * __expf(m - mn) + cl * __expf(cm - mn);
    m = mn;
  }
  float invl = 1.f / l;
  float a0 = 0.f, a1 = 0.f;
  int half = lane >> 5, hl = lane & 31;
  for (int j0 = beg; j0 < end; j0 += 64) {
    asm volatile("s_waitcnt lgkmcnt(0)" ::: "memory");
    int j = j0 + lane;
    if (j < end) {
      int s = col[j];
      float t = as[s] + adn;
      float e = t > 0.f ? t : kSlope * t;
      float w = __expf(e - m) * invl;
      swb[wave][lane] = int2{s, (int)__float_as_int(w)};
    }
    asm volatile("s_waitcnt lgkmcnt(0)" ::: "memory");
    int cntc = min(64, end - j0);
    if (F == 128) {
      for (int k = 0; k < cntc; ++k) {
        int2 p = swb[wave][k];
        float w = __int_as_float(p.y);
        unsigned int v = ((const unsigned int*)(h + (size_t)p.x * 128))[lane];
        a0 += w * bf2f((unsigned short)(v & 0xffffu));
        a1 += w * bf2f((unsigned short)(v >> 16));
      }
    } else {
      for (int k = 0; k < cntc; k += 2) {
        int kk = k + half;
        if (kk < cntc) {
          int2 p = swb[wave][kk];
          float w = __int_as_float(p.y);
          unsigned int v = ((const unsigned int*)(h + (size_t)p.x * 64))[hl];
          a0 += w * bf2f((unsigned short)(v & 0xffffu));
          a1 += w * bf2f((unsigned short)(v >> 16));
        }
      }
    }
  }
  if (F == 128) {
    float o0 = fmaxf(a0 + bias[2 * lane], 0.f);
    float o1 = fmaxf(a1 + bias[2 * lane + 1], 0.f);
    ((unsigned int*)(out + (size_t)nout * 128))[lane] = packbf2(o0, o1);
  } else {
    a0 += __shfl_xor(a0, 32);
    a1 += __shfl_xor(a1, 32);
    if (half == 0) {
      float o0 = fmaxf(a0 + bias[2 * hl], 0.f);
      float o1 = fmaxf(a1 + bias[2 * hl + 1], 0.f);
      ((unsigned int*)(out + (size_t)nout * 64))[hl] = packbf2(o0, o1);
    }
  }
}

// ---------------- fused FC head: fc1 (MFMA) -> LDS -> fc2 (register weights) ----------------
__global__ __launch_bounds__(256) void k_fc(const unsigned short* __restrict__ o2m,
                                            const unsigned short* __restrict__ Wf,
                                            const float* __restrict__ fc1b,
                                            const float* __restrict__ fc2w,
                                            const float* __restrict__ fc2b,
                                            float* __restrict__ out) {
  __shared__ unsigned short tile[4][16 * 128];   // 16 KB
  int wave = threadIdx.x >> 6, lane = threadIdx.x & 63;
  int strip = blockIdx.x * 4 + wave;
  if (strip >= kM / 16) return;
  int r0 = strip * 16;
  int m = lane & 15, quad = lane >> 4;
  const short8* xs = (const short8*)(o2m + (size_t)(r0 + m) * 64);
  short8 a0 = xs[quad], a1 = xs[quad + 4];
  const short8* wf = (const short8*)Wf;
  floatx4 acc[8];
#pragma unroll
  for (int nt = 0; nt < 8; ++nt) acc[nt] = floatx4{0.f, 0.f, 0.f, 0.f};
#pragma unroll
  for (int nt = 0; nt < 8; ++nt) {
    acc[nt] = __builtin_amdgcn_mfma_f32_16x16x32_bf16(a0, wf[(0 * 8 + nt) * 64 + lane], acc[nt], 0, 0, 0);
    acc[nt] = __builtin_amdgcn_mfma_f32_16x16x32_bf16(a1, wf[(1 * 8 + nt) * 64 + lane], acc[nt], 0, 0, 0);
  }
  unsigned short* tw = tile[wave];
#pragma unroll
  for (int nt = 0; nt < 8; ++nt) {
    float bb = fc1b[nt * 16 + m];
#pragma unroll
    for (int reg = 0; reg < 4; ++reg)
      tw[(quad * 4 + reg) * 128 + nt * 16 + m] = f2bf1(fmaxf(acc[nt][reg] + bb, 0.f));
  }
  asm volatile("s_waitcnt lgkmcnt(0)" ::: "memory");   // z tile visible to this wave
  // fc2: c = lane&15 (class, <10 active), q = lane>>4 (k-quarter)
  int c = lane & 15, q = lane >> 4;
  bool active = c < 10;
  float wreg[32];
#pragma unroll
  for (int i = 0; i < 32; ++i)
    wreg[i] = active ? fc2w[(q * 32 + i) * 10 + c] : 0.f;
  float bc = active ? fc2b[c] : 0.f;
  for (int r = 0; r < 16; ++r) {
    const uint2* zr = (const uint2*)(tw + r * 128 + q * 32);
    float acc2 = 0.f;
#pragma unroll
    for (int i = 0; i < 8; ++i) {
      uint2 v = zr[i];                       // 16 lanes broadcast same LDS addr
      acc2 += bf2f((unsigned short)(v.x & 0xffffu)) * wreg[4 * i]
            + bf2f((unsigned short)(v.x >> 16))     * wreg[4 * i + 1]
            + bf2f((unsigned short)(v.y & 0xffffu)) * wreg[4 * i + 2]
            + bf2f((unsigned short)(v.y >> 16))     * wreg[4 * i + 3];
    }
    acc2 += __shfl_xor(acc2, 16);
    acc2 += __shfl_xor(acc2, 32);
    if (q == 0 && active) out[(size_t)(r0 + r) * 10 + c] = acc2 + bc;
  }
}

extern "C" void kernel_launch(void* const* d_in, const int* in_sizes, int n_in,
                              void* d_out, int out_size, void* d_ws, size_t ws_size,
                              hipStream_t stream) {
  const float* x     = (const float*)d_in[0];
  const int*   ei    = (const int*)d_in[1];     // [2,E] as int32 (harness converts)
  const int*   mask  = (const int*)d_in[2];
  const float* W1    = (const float*)d_in[3];
  const float* asrc1 = (const float*)d_in[4];
  const float* adst1 = (const float*)d_in[5];
  const float* b1    = (const float*)d_in[6];
  const float* W2    = (const float*)d_in[7];
  const float* asrc2 = (const float*)d_in[8];
  const float* adst2 = (const float*)d_in[9];
  const float* b2    = (const float*)d_in[10];
  const float* fc1w  = (const float*)d_in[11];
  const float* fc1b  = (const float*)d_in[12];
  const float* fc2w  = (const float*)d_in[13];
  const float* fc2b  = (const float*)d_in[14];
  float* out = (float*)d_out;

  const int* esrc = ei;
  const int* edst = ei + kE;

  // -------- workspace layout (total ~72 MB) --------
  char* ws = (char*)d_ws;
  size_t off = 0;
  auto alloc = [&](size_t bytes) -> void* {
    void* p = ws + off;
    off = (off + bytes + 255) & ~(size_t)255;
    return p;
  };
  unsigned short* Wf1     = (unsigned short*)alloc(128 * 128 * 2);        // 32 KB
  unsigned short* Wf2     = (unsigned short*)alloc(128 * 64 * 2);         // 16 KB
  unsigned short* Wf3     = (unsigned short*)alloc(64 * 128 * 2);         // 16 KB (fc1)
  int*            rstart  = (int*)alloc((size_t)kN * 4);                  // 0.4 MB
  int*            degA    = (int*)alloc((size_t)kN * 4);                  // 0.4 MB
  int*            bcursor = (int*)alloc((size_t)kNB * 4);                 // 3.1 KB
  float*          as1     = (float*)alloc((size_t)kN * 4);
  float*          ad1     = (float*)alloc((size_t)kN * 4);
  float*          as2     = (float*)alloc((size_t)kN * 4);
  float*          ad2     = (float*)alloc((size_t)kN * 4);                // 1.6 MB total
  int*            pairs   = (int*)alloc((size_t)kNB * kBCap * 4);         // 9.6 MB (becomes colidx)
  unsigned short* h1      = (unsigned short*)alloc((size_t)kN * 128 * 2); // 25.6 MB
  unsigned short* o1      = (unsigned short*)alloc((size_t)kN * 128 * 2); // 25.6 MB
  // h2/o2m alias the h1 region (h1 dead after k_agg<128>)
  unsigned short* h2  = h1;                        // 12.8 MB
  unsigned short* o2m = h1 + (size_t)kN * 64;      // 2.56 MB (compact masked rows)
  (void)ws_size; (void)in_sizes; (void)n_in; (void)out_size;

  const int nodeBlocks = (kN + 3) / 4;
  const int maskBlocks = (kM + 3) / 4;

  // 1) setup: weight swizzles + zero bcursor
  k_setup<<<128, 256, 0, stream>>>(W1, W2, fc1w, Wf1, Wf2, Wf3, bcursor);
  // 2) fat kernel: edge scatter U gemm1
  k_sg1<<<kSB + kG1B, 256, 0, stream>>>(esrc, edst, bcursor, pairs,
                                        x, Wf1, asrc1, adst1, h1, as1, ad1);
  // 3) bucket CSR finalize (in-place)
  k_bucket_csr<<<kNB, 256, 0, stream>>>(pairs, bcursor, rstart, degA);
  // 4) layer-1 aggregation
  k_agg<128, false><<<nodeBlocks, 256, 0, stream>>>(h1, rstart, degA, pairs,
                                                    as1, ad1, b1, o1, nullptr);
  // 5) layer-2 GEMM
  k_gemm2<<<kG1B, 256, 0, stream>>>(o1, Wf2, asrc2, adst2, h2, as2, ad2);
  // 6) layer-2 aggregation, masked rows only
  k_agg<64, true><<<maskBlocks, 256, 0, stream>>>(h2, rstart, degA, pairs,
                                                  as2, ad2, b2, o2m, mask);
  // 7) fused FC head
  k_fc<<<(kM / 16 + 3) / 4, 256, 0, stream>>>(o2m, Wf3, fc1b, fc2w, fc2b, out);
}